// Round 3
// baseline (16.295 us; speedup 1.0000x reference)
//
#include <hip/hip_runtime.h>

#define BB 2
#define CC 4
#define TT 128
#define VV 67
#define FF 64
#define NCLS 100
#define TV 8576   // T*V == V*T
#define QQ 134    // TV / FF

// Kernel A: z[b, v*T + t] = relu(vc2_w*(sum_c vel*vc1_w + vc1_b) + vc2_b)
//                         + relu(sc2_w*(sum_c joint*sc1_w + sc1_b) + sc2_b)
// Inputs fp32 (reference is jnp.float32); z stored fp32 in workspace.
__global__ void ar_compute_z(const float* __restrict__ joint,
                             const float* __restrict__ vel,
                             const float* __restrict__ vc1_w, const float* __restrict__ vc1_b,
                             const float* __restrict__ vc2_w, const float* __restrict__ vc2_b,
                             const float* __restrict__ sc1_w, const float* __restrict__ sc1_b,
                             const float* __restrict__ sc2_w, const float* __restrict__ sc2_b,
                             float* __restrict__ z_out) {
    int l = blockIdx.x * blockDim.x + threadIdx.x;
    if (l >= BB * TV) return;
    int b = l / TV;
    int r = l % TV;          // r = t*V + v  (coalesced over input layout)
    int t = r / VV;
    int v = r % VV;
    const int base = b * (CC * TV) + r;

    float vs = vc1_b[0];
    vs += vel[base + 0 * TV] * vc1_w[0];
    vs += vel[base + 1 * TV] * vc1_w[1];
    vs += vel[base + 2 * TV] * vc1_w[2];
    vs += vel[base + 3 * TV] * vc1_w[3];

    float js = sc1_b[0];
    js += joint[base + 0 * TV] * sc1_w[0];
    js += joint[base + 1 * TV] * sc1_w[1];
    js += joint[base + 2 * TV] * sc1_w[2];
    js += joint[base + 3 * TV] * sc1_w[3];

    float Velv = fmaxf(vc2_w[0] * vs + vc2_b[0], 0.0f);
    float Iv   = fmaxf(sc2_w[0] * js + sc2_b[0], 0.0f);

    z_out[b * TV + v * TT + t] = Velv + Iv;   // store in p = v*T + t ordering
}

// Kernel B: rank-1 attention collapse + head + softmax. Single block.
//   scores[b,p,j] = relu(z[b,p]*u[b,j]) = z[b,p]*relu(u[b,j])  (z >= 0)
//   u[b,j] = w_void[j&63] * A[b, j>>6],  A[b,q] = sum_f w_theta[f]*z[b, f*QQ+q]
//   att[b,p,f] = z[b,p]*w_g[f]*S[b],     S[b]   = sum_j relu(u[b,j])*z[b,j]
//   pooled[b,c] = Zmean[b]*(S[b]*gw[c] + 1) + convh_b[c]
__global__ __launch_bounds__(1024) void ar_finish(
    const float* __restrict__ z,            // [B][TV], p = v*T+t
    const float* __restrict__ w_theta, const float* __restrict__ w_void,
    const float* __restrict__ w_g,
    const float* __restrict__ convh_w, const float* __restrict__ convh_b,
    const float* __restrict__ lin_w, const float* __restrict__ lin_b,
    float* __restrict__ out) {
    __shared__ float wth[FF], wvd[FF];
    __shared__ float A[BB * QQ];            // 268
    __shared__ float red[64];               // 16 waves x 4 quantities
    __shared__ float Sv[BB], Zm[BB];
    __shared__ float pooled[BB * CC];
    __shared__ float logits[BB * NCLS];
    __shared__ float evals[BB * NCLS];
    __shared__ float smax[BB], sinv[BB];

    const int tid = threadIdx.x;

    if (tid < FF) { wth[tid] = w_theta[tid]; wvd[tid] = w_void[tid]; }
    __syncthreads();

    // A[b,q] = sum_f w_theta[f] * z[b, f*134 + q]
    if (tid < BB * QQ) {
        int b = tid / QQ, q = tid % QQ;
        const float* zb = z + b * TV;
        float acc = 0.0f;
        #pragma unroll
        for (int f = 0; f < FF; ++f) acc += wth[f] * zb[f * QQ + q];
        A[tid] = acc;
    }
    __syncthreads();

    // S[b] = sum_j relu(w_void[j&63] * A[b, j>>6]) * z[b,j];  Zsum[b] = sum_j z[b,j]
    float sS0 = 0.f, sS1 = 0.f, sZ0 = 0.f, sZ1 = 0.f;
    for (int j = tid; j < TV; j += 1024) {
        float wv = wvd[j & 63];
        int q = j >> 6;
        float z0 = z[j], z1 = z[TV + j];
        float u0 = wv * A[q], u1 = wv * A[QQ + q];
        sS0 += fmaxf(u0, 0.f) * z0;
        sS1 += fmaxf(u1, 0.f) * z1;
        sZ0 += z0;
        sZ1 += z1;
    }
    #pragma unroll
    for (int off = 32; off > 0; off >>= 1) {
        sS0 += __shfl_down(sS0, off);
        sS1 += __shfl_down(sS1, off);
        sZ0 += __shfl_down(sZ0, off);
        sZ1 += __shfl_down(sZ1, off);
    }
    int wave = tid >> 6, lane = tid & 63;
    if (lane == 0) {
        red[wave] = sS0; red[16 + wave] = sS1;
        red[32 + wave] = sZ0; red[48 + wave] = sZ1;
    }
    __syncthreads();
    if (tid < 4) {
        float acc = 0.f;
        #pragma unroll
        for (int w = 0; w < 16; ++w) acc += red[tid * 16 + w];
        if (tid == 0) Sv[0] = acc;
        else if (tid == 1) Sv[1] = acc;
        else if (tid == 2) Zm[0] = acc / (float)TV;
        else Zm[1] = acc / (float)TV;
    }
    __syncthreads();

    // pooled[b,c] = Zmean[b]*(S[b]*gw[c] + 1) + convh_b[c],  gw[c] = sum_f convh_w[c,f]*w_g[f]
    if (tid < BB * CC) {
        int b = tid / CC, c = tid % CC;
        float gw = 0.f;
        #pragma unroll
        for (int f = 0; f < FF; ++f) gw += convh_w[c * FF + f] * w_g[f];
        pooled[tid] = Zm[b] * (Sv[b] * gw + 1.0f) + convh_b[c];
    }
    __syncthreads();

    // logits[b,n] = lin_b[n] + sum_c lin_w[n,c]*pooled[b,c]
    if (tid < BB * NCLS) {
        int b = tid / NCLS, n = tid % NCLS;
        float lg = lin_b[n];
        #pragma unroll
        for (int c = 0; c < CC; ++c) lg += lin_w[n * CC + c] * pooled[b * CC + c];
        logits[tid] = lg;
    }
    __syncthreads();
    if (tid < BB) {
        float m = -1e30f;
        for (int n = 0; n < NCLS; ++n) m = fmaxf(m, logits[tid * NCLS + n]);
        smax[tid] = m;
    }
    __syncthreads();
    if (tid < BB * NCLS) {
        int b = tid / NCLS;
        evals[tid] = expf(logits[tid] - smax[b]);
    }
    __syncthreads();
    if (tid < BB) {
        float s = 0.f;
        for (int n = 0; n < NCLS; ++n) s += evals[tid * NCLS + n];
        sinv[tid] = 1.0f / s;
    }
    __syncthreads();
    if (tid < BB * NCLS) {
        int b = tid / NCLS;
        out[tid] = evals[tid] * sinv[b];   // fp32 output
    }
}

extern "C" void kernel_launch(void* const* d_in, const int* in_sizes, int n_in,
                              void* d_out, int out_size, void* d_ws, size_t ws_size,
                              hipStream_t stream) {
    const float* joint  = (const float*)d_in[0];
    const float* vel    = (const float*)d_in[1];
    const float* vc1_w  = (const float*)d_in[2];
    const float* vc1_b  = (const float*)d_in[3];
    const float* vc2_w  = (const float*)d_in[4];
    const float* vc2_b  = (const float*)d_in[5];
    const float* sc1_w  = (const float*)d_in[6];
    const float* sc1_b  = (const float*)d_in[7];
    const float* sc2_w  = (const float*)d_in[8];
    const float* sc2_b  = (const float*)d_in[9];
    const float* w_theta = (const float*)d_in[10];
    const float* w_void  = (const float*)d_in[11];
    const float* w_g     = (const float*)d_in[12];
    const float* convh_w = (const float*)d_in[13];
    const float* convh_b = (const float*)d_in[14];
    const float* lin_w   = (const float*)d_in[15];
    const float* lin_b   = (const float*)d_in[16];
    float* out = (float*)d_out;

    float* zws = (float*)d_ws;   // B*TV floats = 68,608 bytes

    const int total = BB * TV;   // 17152
    dim3 gridA((total + 255) / 256), blockA(256);
    ar_compute_z<<<gridA, blockA, 0, stream>>>(joint, vel, vc1_w, vc1_b, vc2_w, vc2_b,
                                               sc1_w, sc1_b, sc2_w, sc2_b, zws);

    ar_finish<<<1, 1024, 0, stream>>>(zws, w_theta, w_void, w_g,
                                      convh_w, convh_b, lin_w, lin_b, out);
}

// Round 4
// 12.922 us; speedup vs baseline: 1.2610x; 1.2610x over previous
//
#include <hip/hip_runtime.h>

#define BB 2
#define CC 4
#define TT 128
#define VV 67
#define FF 64
#define NCLS 100
#define TV 8576   // T*V == V*T
#define QQ 134    // TV / FF

// Padded LDS accessor for z stored at p = v*128 + t:
// idx(p) = v*129 + t = p + (p>>7). Makes the transpose store and all
// strided readers bank-conflict-free (bank = (v + t) % 32 spreads).
#define ZIDX(p) ((p) + ((p) >> 7))
#define ZLDS (TV + VV)   // 8643 floats

// Whole model, one kernel. Block b handles batch b (fully batch-separable):
//   z[p] = relu(vc2*(sum_c vel*vc1)+...) + relu(sc2*(sum_c joint*sc1)+...)
//   scores rank-1 (z>=0):  scores[p,j] = z[p]*relu(wvd[j&63]*A[j>>6])
//   A[q]  = sum_f wth[f]*z[f*QQ+q]
//   S     = sum_j relu(u[j])*z[j]
//   pooled[c] = Zmean*(S*gw[c]+1) + convh_b[c],  gw[c]=sum_f convh_w[c,f]*wg[f]
//   logits -> softmax -> out[b*100..]
__global__ __launch_bounds__(1024) void ar_fused(
    const float* __restrict__ joint, const float* __restrict__ vel,
    const float* __restrict__ vc1_w, const float* __restrict__ vc1_b,
    const float* __restrict__ vc2_w, const float* __restrict__ vc2_b,
    const float* __restrict__ sc1_w, const float* __restrict__ sc1_b,
    const float* __restrict__ sc2_w, const float* __restrict__ sc2_b,
    const float* __restrict__ w_theta, const float* __restrict__ w_void,
    const float* __restrict__ w_g,
    const float* __restrict__ convh_w, const float* __restrict__ convh_b,
    const float* __restrict__ lin_w, const float* __restrict__ lin_b,
    float* __restrict__ out)
{
    const int b = blockIdx.x;
    const int tid = threadIdx.x;

    __shared__ float zs[ZLDS];          // 34,572 B
    __shared__ float wth[FF], wvd[FF];
    __shared__ float A[QQ];
    __shared__ float redS[16], redZ[16];
    __shared__ float Sv, Zm;
    __shared__ float pooled[CC];
    __shared__ float logits[NCLS], evals[NCLS];
    __shared__ float smax, sinv;

    if (tid < FF) { wth[tid] = w_theta[tid]; wvd[tid] = w_void[tid]; }

    // uniform scalar weights (compiler scalarizes; L2-resident)
    const float v1w0 = vc1_w[0], v1w1 = vc1_w[1], v1w2 = vc1_w[2], v1w3 = vc1_w[3];
    const float s1w0 = sc1_w[0], s1w1 = sc1_w[1], s1w2 = sc1_w[2], s1w3 = sc1_w[3];
    const float v1b = vc1_b[0], v2w = vc2_w[0], v2b = vc2_b[0];
    const float s1b = sc1_b[0], s2w = sc2_w[0], s2b = sc2_b[0];

    // ---- Phase 1: z into LDS (transposed to p = v*T + t), fused Zsum ----
    const float4* velb = (const float4*)(vel + (size_t)b * CC * TV);
    const float4* jntb = (const float4*)(joint + (size_t)b * CC * TV);
    const int P4 = TV / 4;   // 2144 float4 per channel plane

    float zacc = 0.0f;
    for (int i = tid; i < P4; i += 1024) {
        float4 vA = velb[i];            float4 jA = jntb[i];
        float4 vB = velb[i + P4];       float4 jB = jntb[i + P4];
        float4 vC = velb[i + 2 * P4];   float4 jC = jntb[i + 2 * P4];
        float4 vD = velb[i + 3 * P4];   float4 jD = jntb[i + 3 * P4];

        float zv[4];
        {
            float vs, js;
            vs = v1b + vA.x * v1w0 + vB.x * v1w1 + vC.x * v1w2 + vD.x * v1w3;
            js = s1b + jA.x * s1w0 + jB.x * s1w1 + jC.x * s1w2 + jD.x * s1w3;
            zv[0] = fmaxf(v2w * vs + v2b, 0.f) + fmaxf(s2w * js + s2b, 0.f);
            vs = v1b + vA.y * v1w0 + vB.y * v1w1 + vC.y * v1w2 + vD.y * v1w3;
            js = s1b + jA.y * s1w0 + jB.y * s1w1 + jC.y * s1w2 + jD.y * s1w3;
            zv[1] = fmaxf(v2w * vs + v2b, 0.f) + fmaxf(s2w * js + s2b, 0.f);
            vs = v1b + vA.z * v1w0 + vB.z * v1w1 + vC.z * v1w2 + vD.z * v1w3;
            js = s1b + jA.z * s1w0 + jB.z * s1w1 + jC.z * s1w2 + jD.z * s1w3;
            zv[2] = fmaxf(v2w * vs + v2b, 0.f) + fmaxf(s2w * js + s2b, 0.f);
            vs = v1b + vA.w * v1w0 + vB.w * v1w1 + vC.w * v1w2 + vD.w * v1w3;
            js = s1b + jA.w * s1w0 + jB.w * s1w1 + jC.w * s1w2 + jD.w * s1w3;
            zv[3] = fmaxf(v2w * vs + v2b, 0.f) + fmaxf(s2w * js + s2b, 0.f);
        }

        int r = 4 * i;
        int t = r / VV, v = r - t * VV;
        #pragma unroll
        for (int k = 0; k < 4; ++k) {
            int p = (v << 7) + t;
            zs[ZIDX(p)] = zv[k];
            zacc += zv[k];
            if (++v == VV) { v = 0; ++t; }
        }
    }
    __syncthreads();

    // ---- Phase 2: A[q] = sum_f wth[f] * z[f*QQ + q] ----
    if (tid < QQ) {
        float acc = 0.0f;
        #pragma unroll
        for (int f = 0; f < FF; ++f) {
            int p = f * QQ + tid;
            acc += wth[f] * zs[ZIDX(p)];
        }
        A[tid] = acc;
    }
    __syncthreads();

    // ---- Phase 3: S = sum_j relu(wvd[j&63]*A[j>>6]) * z[j]; finish Zsum ----
    float sS = 0.0f;
    for (int j = tid; j < TV; j += 1024) {
        float u = wvd[j & 63] * A[j >> 6];
        sS += fmaxf(u, 0.0f) * zs[ZIDX(j)];
    }
    #pragma unroll
    for (int off = 32; off > 0; off >>= 1) {
        sS += __shfl_down(sS, off);
        zacc += __shfl_down(zacc, off);
    }
    if ((tid & 63) == 0) { redS[tid >> 6] = sS; redZ[tid >> 6] = zacc; }
    __syncthreads();
    if (tid == 0) {
        float aS = 0.f, aZ = 0.f;
        #pragma unroll
        for (int w = 0; w < 16; ++w) { aS += redS[w]; aZ += redZ[w]; }
        Sv = aS;
        Zm = aZ / (float)TV;
    }
    __syncthreads();

    // ---- Phase 4: pooled -> logits -> softmax -> out ----
    if (tid < CC) {
        float gw = 0.f;
        #pragma unroll
        for (int f = 0; f < FF; ++f) gw += convh_w[tid * FF + f] * w_g[f];
        pooled[tid] = Zm * (Sv * gw + 1.0f) + convh_b[tid];
    }
    __syncthreads();
    if (tid < NCLS) {
        float lg = lin_b[tid];
        #pragma unroll
        for (int c = 0; c < CC; ++c) lg += lin_w[tid * CC + c] * pooled[c];
        logits[tid] = lg;
    }
    __syncthreads();
    if (tid == 0) {
        float m = -1e30f;
        for (int n = 0; n < NCLS; ++n) m = fmaxf(m, logits[n]);
        smax = m;
    }
    __syncthreads();
    if (tid < NCLS) evals[tid] = expf(logits[tid] - smax);
    __syncthreads();
    if (tid == 0) {
        float s = 0.f;
        for (int n = 0; n < NCLS; ++n) s += evals[n];
        sinv = 1.0f / s;
    }
    __syncthreads();
    if (tid < NCLS) out[b * NCLS + tid] = evals[tid] * sinv;
}

extern "C" void kernel_launch(void* const* d_in, const int* in_sizes, int n_in,
                              void* d_out, int out_size, void* d_ws, size_t ws_size,
                              hipStream_t stream) {
    const float* joint  = (const float*)d_in[0];
    const float* vel    = (const float*)d_in[1];
    const float* vc1_w  = (const float*)d_in[2];
    const float* vc1_b  = (const float*)d_in[3];
    const float* vc2_w  = (const float*)d_in[4];
    const float* vc2_b  = (const float*)d_in[5];
    const float* sc1_w  = (const float*)d_in[6];
    const float* sc1_b  = (const float*)d_in[7];
    const float* sc2_w  = (const float*)d_in[8];
    const float* sc2_b  = (const float*)d_in[9];
    const float* w_theta = (const float*)d_in[10];
    const float* w_void  = (const float*)d_in[11];
    const float* w_g     = (const float*)d_in[12];
    const float* convh_w = (const float*)d_in[13];
    const float* convh_b = (const float*)d_in[14];
    const float* lin_w   = (const float*)d_in[15];
    const float* lin_b   = (const float*)d_in[16];
    float* out = (float*)d_out;

    ar_fused<<<BB, 1024, 0, stream>>>(joint, vel, vc1_w, vc1_b, vc2_w, vc2_b,
                                      sc1_w, sc1_b, sc2_w, sc2_b,
                                      w_theta, w_void, w_g,
                                      convh_w, convh_b, lin_w, lin_b, out);
}